// Round 6
// baseline (556.040 us; speedup 1.0000x reference)
//
#include <hip/hip_runtime.h>
#include <hip/hip_bf16.h>

#define NEG 0.2f

typedef __attribute__((ext_vector_type(8))) short bf16x8;
typedef __attribute__((ext_vector_type(4))) float f32x4;

static __device__ __forceinline__ unsigned short f2bf(float f) {
    union { float f; unsigned u; } v; v.f = f;
    unsigned r = v.u + 0x7fff + ((v.u >> 16) & 1);
    return (unsigned short)(r >> 16);
}
static __device__ __forceinline__ float bf2f(unsigned short h) {
    return __uint_as_float((unsigned)h << 16);
}

// ---------------------------------------------------------------- init
__global__ void k_zero(int* __restrict__ deg, float* __restrict__ h2,
                       int* __restrict__ total, int n) {
    int i = blockIdx.x * 256 + threadIdx.x;
    if (i < n) deg[i] = 0;
    if (i < 2 * n) h2[i] = 0.f;
    if (i == 0) *total = 0;
}

__global__ void k_count(const int* __restrict__ ei, int* __restrict__ deg,
                        int E_, int n) {
    int e = blockIdx.x * 256 + threadIdx.x;
    int tot = E_ + n;
    if (e >= tot) return;
    int d = (e < E_) ? ei[E_ + e] : (e - E_);
    atomicAdd(&deg[d], 1);
}

// parallel offset assignment (order-free CSR: offs need not be monotone)
__global__ void k_assign(const int* __restrict__ deg, int* __restrict__ offs,
                         int* __restrict__ cursor, int* __restrict__ total, int n) {
    int v = blockIdx.x * 256 + threadIdx.x;
    if (v >= n) return;
    int d = deg[v];
    int base = atomicAdd(total, d);
    offs[v] = base; cursor[v] = base;
}

__global__ void k_scatter(const int* __restrict__ ei, int* __restrict__ cursor,
                          int* __restrict__ csr, int E_, int n) {
    int e = blockIdx.x * 256 + threadIdx.x;
    int tot = E_ + n;
    if (e >= tot) return;
    int s, d;
    if (e < E_) { s = ei[e]; d = ei[E_ + e]; } else { s = d = e - E_; }
    int pos = atomicAdd(&cursor[d], 1);
    csr[pos] = s;
}

// ---------------------------------------------------------------- weight prep
// W1 [128][512] -> W1t bf16 [512][128]
__global__ void k_cast_wt(const float* __restrict__ W, unsigned short* __restrict__ wt) {
    int i = blockIdx.x * 256 + threadIdx.x;   // 65536
    int c = i >> 7, k = i & 127;
    wt[i] = f2bf(W[k * 512 + c]);
}

// c[col,k] = sum_cc W1[k, h*64+cc] * a[h,cc]; col = h (+8 for dst).
// hi/lo bf16 split for near-fp32 MFMA scores.
__global__ void k_prep_c(const float* __restrict__ W1, const float* __restrict__ a_src,
                         const float* __restrict__ a_dst,
                         unsigned short* __restrict__ cbhi,
                         unsigned short* __restrict__ cblo) {
    int t = blockIdx.x * 256 + threadIdx.x;   // 2048
    if (t >= 2048) return;
    int which = t >> 10, rem = t & 1023;
    int h = rem >> 7, k = rem & 127;
    const float* a = which ? a_dst : a_src;
    float s = 0.f;
    #pragma unroll 8
    for (int cc = 0; cc < 64; cc++)
        s = fmaf(W1[k * 512 + h * 64 + cc], a[h * 64 + cc], s);
    unsigned short hi = f2bf(s);
    unsigned short lo = f2bf(s - bf2f(hi));
    cbhi[(which * 8 + h) * 128 + k] = hi;
    cblo[(which * 8 + h) * 128 + k] = lo;
}

// ---------------------------------------------------------------- alpha (MFMA, hi/lo)
// [as1|ad1][row, 0..16] = x[row,128] @ c^T with split-bf16 precision (~fp32).
__global__ __launch_bounds__(256) void k_alpha(const float* __restrict__ x,
                                               const unsigned short* __restrict__ cbhi,
                                               const unsigned short* __restrict__ cblo,
                                               float* __restrict__ as1,
                                               float* __restrict__ ad1, int n) {
    int tid = threadIdx.x, wave = tid >> 6, lane = tid & 63;
    int l15 = lane & 15, q = lane >> 4;
    int row0 = blockIdx.x * 64 + wave * 16;
    int rr = row0 + l15; if (rr > n - 1) rr = n - 1;   // clamp (guarded at store)
    f32x4 acc = {};
    const float* ap = x + (size_t)rr * 128 + q * 8;
    const unsigned short* bph = cbhi + (size_t)l15 * 128 + q * 8;
    const unsigned short* bpl = cblo + (size_t)l15 * 128 + q * 8;
    #pragma unroll
    for (int kb = 0; kb < 4; kb++) {
        float4 v0 = *(const float4*)(ap + kb * 32);
        float4 v1 = *(const float4*)(ap + kb * 32 + 4);
        float xv[8] = {v0.x, v0.y, v0.z, v0.w, v1.x, v1.y, v1.z, v1.w};
        bf16x8 ahi, alo;
        #pragma unroll
        for (int j = 0; j < 8; j++) {
            unsigned short h = f2bf(xv[j]);
            ahi[j] = (short)h;
            alo[j] = (short)f2bf(xv[j] - bf2f(h));
        }
        bf16x8 bh = *(const bf16x8*)(bph + kb * 32);
        bf16x8 bl = *(const bf16x8*)(bpl + kb * 32);
        acc = __builtin_amdgcn_mfma_f32_16x16x32_bf16(ahi, bh, acc, 0, 0, 0);
        acc = __builtin_amdgcn_mfma_f32_16x16x32_bf16(ahi, bl, acc, 0, 0, 0);
        acc = __builtin_amdgcn_mfma_f32_16x16x32_bf16(alo, bh, acc, 0, 0, 0);
    }
    #pragma unroll
    for (int r = 0; r < 4; r++) {
        int row = row0 + q * 4 + r;
        if (row < n) {
            if (l15 < 8) as1[row * 8 + l15] = acc[r];
            else         ad1[row * 8 + (l15 - 8)] = acc[r];
        }
    }
}

// ---------------------------------------------------------------- fused agg+GEMM
// Block = 8 dst nodes, 4 waves. Phase 1: wave w aggregates nodes {2w,2w+1} in
// x-space (fp32 gather, fp32 acc) -> LDS fp32. Phase 2: wave w runs heads
// {2w,2w+1}: A = LDS (hi/lo split), B = w1t; ELU + W2 projection fused;
// atomicAdd into h2. aggx never touches HBM.
#define NPITCH 1064   // floats per node in LDS (8*132 + 8 skew)
#define HPITCH 132    // floats per head
__global__ __launch_bounds__(256) void k_fused(const float* __restrict__ x,
                                               const float* __restrict__ as1,
                                               const float* __restrict__ ad1,
                                               const unsigned short* __restrict__ w1t,
                                               const float* __restrict__ b1,
                                               const float* __restrict__ W2,
                                               const int* __restrict__ offs,
                                               const int* __restrict__ deg,
                                               const int* __restrict__ csr,
                                               float* __restrict__ h2, int n) {
    __shared__ float lds[8 * NPITCH];
    int tid = threadIdx.x, wave = tid >> 6, lane = tid & 63;
    int h = lane >> 3, j = lane & 7;
    int v0 = blockIdx.x * 8;

    // ---- phase 1: aggregate 2 nodes per wave
    for (int t2 = 0; t2 < 2; t2++) {
        int nl = wave * 2 + t2;
        int v = v0 + nl;
        float acc[16] = {};
        float s = 0.f;
        if (v < n) {
            int s0 = offs[v], e1 = s0 + deg[v];
            float adh = ad1[v * 8 + h];
            for (int i = s0; i < e1; i++) {
                int u = csr[i];
                float e = as1[u * 8 + h] + adh;
                e = (e >= 0.f) ? e : NEG * e;
                float w = __expf(e);
                s += w;
                const float4* xp = (const float4*)(x + (size_t)u * 128 + j * 16);
                float4 a0 = xp[0], a1 = xp[1], a2 = xp[2], a3 = xp[3];
                acc[0]  = fmaf(w, a0.x, acc[0]);
                acc[1]  = fmaf(w, a0.y, acc[1]);
                acc[2]  = fmaf(w, a0.z, acc[2]);
                acc[3]  = fmaf(w, a0.w, acc[3]);
                acc[4]  = fmaf(w, a1.x, acc[4]);
                acc[5]  = fmaf(w, a1.y, acc[5]);
                acc[6]  = fmaf(w, a1.z, acc[6]);
                acc[7]  = fmaf(w, a1.w, acc[7]);
                acc[8]  = fmaf(w, a2.x, acc[8]);
                acc[9]  = fmaf(w, a2.y, acc[9]);
                acc[10] = fmaf(w, a2.z, acc[10]);
                acc[11] = fmaf(w, a2.w, acc[11]);
                acc[12] = fmaf(w, a3.x, acc[12]);
                acc[13] = fmaf(w, a3.y, acc[13]);
                acc[14] = fmaf(w, a3.z, acc[14]);
                acc[15] = fmaf(w, a3.w, acc[15]);
            }
        }
        float inv = (s > 0.f) ? 1.0f / s : 0.f;
        float* dst = lds + nl * NPITCH + h * HPITCH + j * 16;
        #pragma unroll
        for (int p = 0; p < 4; p++)
            *(float4*)(dst + p * 4) = make_float4(acc[4 * p] * inv, acc[4 * p + 1] * inv,
                                                  acc[4 * p + 2] * inv, acc[4 * p + 3] * inv);
    }
    __syncthreads();

    // ---- phase 2: 2 heads per wave, MFMA from LDS
    int l15 = lane & 15, q = lane >> 4;
    int nl8 = l15 & 7;
    #pragma unroll
    for (int hi2 = 0; hi2 < 2; hi2++) {
        int hh = wave * 2 + hi2;
        int col0 = hh * 64;
        f32x4 accm[4] = {};
        #pragma unroll
        for (int kb = 0; kb < 4; kb++) {
            const float* asrc = lds + nl8 * NPITCH + hh * HPITCH + kb * 32 + q * 8;
            float4 v0r = *(const float4*)asrc;
            float4 v1r = *(const float4*)(asrc + 4);
            float av[8] = {v0r.x, v0r.y, v0r.z, v0r.w, v1r.x, v1r.y, v1r.z, v1r.w};
            bf16x8 ahi, alo;
            #pragma unroll
            for (int e = 0; e < 8; e++) {
                unsigned short hb = f2bf(av[e]);
                ahi[e] = (short)hb;
                alo[e] = (short)f2bf(av[e] - bf2f(hb));
            }
            #pragma unroll
            for (int t = 0; t < 4; t++) {
                const unsigned short* bp =
                    w1t + (size_t)(col0 + t * 16 + l15) * 128 + kb * 32 + q * 8;
                bf16x8 bf = *(const bf16x8*)bp;
                accm[t] = __builtin_amdgcn_mfma_f32_16x16x32_bf16(ahi, bf, accm[t], 0, 0, 0);
                accm[t] = __builtin_amdgcn_mfma_f32_16x16x32_bf16(alo, bf, accm[t], 0, 0, 0);
            }
        }
        // epilogue: +b1, ELU, project through W2, reduce over 16 cols
        float p0[4] = {}, p1[4] = {};
        #pragma unroll
        for (int t = 0; t < 4; t++) {
            int col = col0 + t * 16 + l15;
            float bb = b1[col];
            float2 w2v = *(const float2*)(W2 + 2 * col);
            #pragma unroll
            for (int r = 0; r < 4; r++) {
                float val = accm[t][r] + bb;
                val = (val > 0.f) ? val : (__expf(val) - 1.0f);
                p0[r] = fmaf(val, w2v.x, p0[r]);
                p1[r] = fmaf(val, w2v.y, p1[r]);
            }
        }
        #pragma unroll
        for (int r = 0; r < 4; r++) {
            #pragma unroll
            for (int off = 1; off < 16; off <<= 1) {
                p0[r] += __shfl_xor(p0[r], off, 64);
                p1[r] += __shfl_xor(p1[r], off, 64);
            }
        }
        if (q < 2 && l15 < 4) {
            float q0 = p0[0], q1 = p1[0];
            if (l15 == 1) { q0 = p0[1]; q1 = p1[1]; }
            if (l15 == 2) { q0 = p0[2]; q1 = p1[2]; }
            if (l15 == 3) { q0 = p0[3]; q1 = p1[3]; }
            int row = q * 4 + l15;          // 0..7
            int node = v0 + row;
            if (node < n) {
                atomicAdd(&h2[2 * node],     q0);
                atomicAdd(&h2[2 * node + 1], q1);
            }
        }
    }
}

// ---------------------------------------------------------------- agg layer 2
// 8 lanes per node (8 nodes per wave, 32 per block).
__global__ __launch_bounds__(256) void k_agg2(const float* __restrict__ h2,
                                              const float* __restrict__ a_src2,
                                              const float* __restrict__ a_dst2,
                                              const float* __restrict__ b2,
                                              const int* __restrict__ offs,
                                              const int* __restrict__ deg,
                                              const int* __restrict__ csr,
                                              float* __restrict__ out, int n) {
    int tid = threadIdx.x;
    int lane = tid & 63, wave = tid >> 6;
    int sub = lane & 7, g = lane >> 3;
    int v = blockIdx.x * 32 + wave * 8 + g;
    if (v >= n) return;
    int s0 = offs[v], s1 = s0 + deg[v];
    float sa0 = a_src2[0], sa1 = a_src2[1];
    float da0 = a_dst2[0], da1 = a_dst2[1];
    float2 hv = *(const float2*)(h2 + 2 * v);
    float adv = hv.x * da0 + hv.y * da1;
    float s = 0.f, a0 = 0.f, a1 = 0.f;
    for (int i = s0 + sub; i < s1; i += 8) {
        int u = csr[i];
        float2 hu = *(const float2*)(h2 + 2 * u);
        float e = hu.x * sa0 + hu.y * sa1 + adv;
        e = (e >= 0.f) ? e : NEG * e;
        float w = __expf(e);
        s += w;
        a0 = fmaf(w, hu.x, a0);
        a1 = fmaf(w, hu.y, a1);
    }
    #pragma unroll
    for (int off = 1; off < 8; off <<= 1) {   // stays within the 8-lane group
        s  += __shfl_xor(s, off, 64);
        a0 += __shfl_xor(a0, off, 64);
        a1 += __shfl_xor(a1, off, 64);
    }
    if (sub == 0) {
        float inv = 1.0f / s;
        out[2 * v]     = a0 * inv + b2[0];
        out[2 * v + 1] = a1 * inv + b2[1];
    }
}

// ---------------------------------------------------------------- launch
extern "C" void kernel_launch(void* const* d_in, const int* in_sizes, int n_in,
                              void* d_out, int out_size, void* d_ws, size_t ws_size,
                              hipStream_t stream) {
    const float* x      = (const float*)d_in[0];
    const int*   ei     = (const int*)d_in[1];
    const float* W1     = (const float*)d_in[2];
    const float* a_src1 = (const float*)d_in[3];
    const float* a_dst1 = (const float*)d_in[4];
    const float* b1     = (const float*)d_in[5];
    const float* W2     = (const float*)d_in[6];
    const float* a_src2 = (const float*)d_in[7];
    const float* a_dst2 = (const float*)d_in[8];
    const float* b2     = (const float*)d_in[9];
    float* out = (float*)d_out;

    int n  = in_sizes[0] / 128;   // 50000
    int E_ = in_sizes[1] / 2;     // 800000
    int tot = E_ + n;
    int rblk = (n + 63) / 64;     // 782

    char* w = (char*)d_ws;
    auto alloc = [&](size_t bytes) {
        char* p = w; w += (bytes + 255) & ~(size_t)255; return p;
    };
    int*            deg    = (int*)alloc((size_t)n * 4);
    int*            offs   = (int*)alloc((size_t)n * 4);
    int*            cursor = (int*)alloc((size_t)n * 4);
    int*            total  = (int*)alloc(256);
    int*            csr    = (int*)alloc((size_t)tot * 4);
    unsigned short* w1t    = (unsigned short*)alloc((size_t)512 * 128 * 2);
    unsigned short* cbhi   = (unsigned short*)alloc((size_t)16 * 128 * 2);
    unsigned short* cblo   = (unsigned short*)alloc((size_t)16 * 128 * 2);
    float*          as1    = (float*)alloc((size_t)n * 8 * 4);
    float*          ad1    = (float*)alloc((size_t)n * 8 * 4);
    float*          h2     = (float*)alloc((size_t)n * 2 * 4);

    int eb = (tot + 255) / 256;
    int zb = (2 * n + 255) / 256;
    int nb256 = (n + 255) / 256;
    k_zero<<<zb, 256, 0, stream>>>(deg, h2, total, n);
    k_count<<<eb, 256, 0, stream>>>(ei, deg, E_, n);
    k_assign<<<nb256, 256, 0, stream>>>(deg, offs, cursor, total, n);
    k_scatter<<<eb, 256, 0, stream>>>(ei, cursor, csr, E_, n);

    k_cast_wt<<<(512 * 128) / 256, 256, 0, stream>>>(W1, w1t);
    k_prep_c<<<8, 256, 0, stream>>>(W1, a_src1, a_dst1, cbhi, cblo);

    k_alpha<<<rblk, 256, 0, stream>>>(x, cbhi, cblo, as1, ad1, n);

    int fb = (n + 7) / 8;
    k_fused<<<fb, 256, 0, stream>>>(x, as1, ad1, w1t, b1, W2, offs, deg, csr, h2, n);

    int ab = (n + 31) / 32;
    k_agg2<<<ab, 256, 0, stream>>>(h2, a_src2, a_dst2, b2, offs, deg, csr, out, n);
}

// Round 7
// 430.910 us; speedup vs baseline: 1.2904x; 1.2904x over previous
//
#include <hip/hip_runtime.h>
#include <hip/hip_bf16.h>

#define NEG 0.2f

typedef __attribute__((ext_vector_type(8))) short bf16x8;
typedef __attribute__((ext_vector_type(4))) float f32x4;

static __device__ __forceinline__ unsigned short f2bf(float f) {
    union { float f; unsigned u; } v; v.f = f;
    unsigned r = v.u + 0x7fff + ((v.u >> 16) & 1);
    return (unsigned short)(r >> 16);
}
static __device__ __forceinline__ float bf2f(unsigned short h) {
    return __uint_as_float((unsigned)h << 16);
}

// ---------------------------------------------------------------- init
__global__ void k_zero(int* __restrict__ deg, float* __restrict__ h2,
                       int* __restrict__ total, int n) {
    int i = blockIdx.x * 256 + threadIdx.x;
    if (i < n) deg[i] = 0;
    if (i < 2 * n) h2[i] = 0.f;
    if (i == 0) *total = 0;
}

__global__ void k_count(const int* __restrict__ ei, int* __restrict__ deg,
                        int E_, int n) {
    int e = blockIdx.x * 256 + threadIdx.x;
    int tot = E_ + n;
    if (e >= tot) return;
    int d = (e < E_) ? ei[E_ + e] : (e - E_);
    atomicAdd(&deg[d], 1);
}

// parallel offset assignment (order-free CSR: offs need not be monotone)
__global__ void k_assign(const int* __restrict__ deg, int* __restrict__ offs,
                         int* __restrict__ cursor, int* __restrict__ total, int n) {
    int v = blockIdx.x * 256 + threadIdx.x;
    if (v >= n) return;
    int d = deg[v];
    int base = atomicAdd(total, d);
    offs[v] = base; cursor[v] = base;
}

__global__ void k_scatter(const int* __restrict__ ei, int* __restrict__ cursor,
                          int* __restrict__ csr, int E_, int n) {
    int e = blockIdx.x * 256 + threadIdx.x;
    int tot = E_ + n;
    if (e >= tot) return;
    int s, d;
    if (e < E_) { s = ei[e]; d = ei[E_ + e]; } else { s = d = e - E_; }
    int pos = atomicAdd(&cursor[d], 1);
    csr[pos] = s;
}

// ---------------------------------------------------------------- weight prep
// W1 [128][512] -> W1t bf16 [512][128]
__global__ void k_cast_wt(const float* __restrict__ W, unsigned short* __restrict__ wt) {
    int i = blockIdx.x * 256 + threadIdx.x;   // 65536
    int c = i >> 7, k = i & 127;
    wt[i] = f2bf(W[k * 512 + c]);
}

// c[col,k] = sum_cc W1[k, h*64+cc] * a[h,cc]; col = h (+8 for dst).
// hi/lo bf16 split for near-fp32 MFMA scores.
__global__ void k_prep_c(const float* __restrict__ W1, const float* __restrict__ a_src,
                         const float* __restrict__ a_dst,
                         unsigned short* __restrict__ cbhi,
                         unsigned short* __restrict__ cblo) {
    int t = blockIdx.x * 256 + threadIdx.x;   // 2048
    if (t >= 2048) return;
    int which = t >> 10, rem = t & 1023;
    int h = rem >> 7, k = rem & 127;
    const float* a = which ? a_dst : a_src;
    float s = 0.f;
    #pragma unroll 8
    for (int cc = 0; cc < 64; cc++)
        s = fmaf(W1[k * 512 + h * 64 + cc], a[h * 64 + cc], s);
    unsigned short hi = f2bf(s);
    unsigned short lo = f2bf(s - bf2f(hi));
    cbhi[(which * 8 + h) * 128 + k] = hi;
    cblo[(which * 8 + h) * 128 + k] = lo;
}

// ---------------------------------------------------------------- alpha (MFMA, hi/lo)
// [as1|ad1][row, 0..16] = x[row,128] @ c^T with split-bf16 precision (~fp32).
__global__ __launch_bounds__(256) void k_alpha(const float* __restrict__ x,
                                               const unsigned short* __restrict__ cbhi,
                                               const unsigned short* __restrict__ cblo,
                                               float* __restrict__ as1,
                                               float* __restrict__ ad1, int n) {
    int tid = threadIdx.x, wave = tid >> 6, lane = tid & 63;
    int l15 = lane & 15, q = lane >> 4;
    int row0 = blockIdx.x * 64 + wave * 16;
    int rr = row0 + l15; if (rr > n - 1) rr = n - 1;   // clamp (guarded at store)
    f32x4 acc = {};
    const float* ap = x + (size_t)rr * 128 + q * 8;
    const unsigned short* bph = cbhi + (size_t)l15 * 128 + q * 8;
    const unsigned short* bpl = cblo + (size_t)l15 * 128 + q * 8;
    #pragma unroll
    for (int kb = 0; kb < 4; kb++) {
        float4 v0 = *(const float4*)(ap + kb * 32);
        float4 v1 = *(const float4*)(ap + kb * 32 + 4);
        float xv[8] = {v0.x, v0.y, v0.z, v0.w, v1.x, v1.y, v1.z, v1.w};
        bf16x8 ahi, alo;
        #pragma unroll
        for (int j = 0; j < 8; j++) {
            unsigned short h = f2bf(xv[j]);
            ahi[j] = (short)h;
            alo[j] = (short)f2bf(xv[j] - bf2f(h));
        }
        bf16x8 bh = *(const bf16x8*)(bph + kb * 32);
        bf16x8 bl = *(const bf16x8*)(bpl + kb * 32);
        acc = __builtin_amdgcn_mfma_f32_16x16x32_bf16(ahi, bh, acc, 0, 0, 0);
        acc = __builtin_amdgcn_mfma_f32_16x16x32_bf16(ahi, bl, acc, 0, 0, 0);
        acc = __builtin_amdgcn_mfma_f32_16x16x32_bf16(alo, bh, acc, 0, 0, 0);
    }
    #pragma unroll
    for (int r = 0; r < 4; r++) {
        int row = row0 + q * 4 + r;
        if (row < n) {
            if (l15 < 8) as1[row * 8 + l15] = acc[r];
            else         ad1[row * 8 + (l15 - 8)] = acc[r];
        }
    }
}

// ---------------------------------------------------------------- agg in x-space
// aggx[v,h,:] = (1/s) sum_u w_uvh * x_u  (fp32 x gather, fp32 acc, hi/lo store).
// One wave per dst node. lane = (g = lane>>5, j = lane&31):
//   channels [4j, 4j+4), heads {g, g+2, g+4, g+6}  (2x replication of the row).
// Weights computed once per edge in lanes 0..7 (head = lane), shfl-broadcast.
__global__ __launch_bounds__(256) void k_aggx(const float* __restrict__ x,
                                              const float* __restrict__ as1,
                                              const float* __restrict__ ad1,
                                              const int* __restrict__ offs,
                                              const int* __restrict__ deg,
                                              const int* __restrict__ csr,
                                              unsigned short* __restrict__ agghi,
                                              unsigned short* __restrict__ agglo, int n) {
    int lane = threadIdx.x & 63;
    int v = blockIdx.x * 4 + (threadIdx.x >> 6);
    if (v >= n) return;
    int g = lane >> 5;          // 0/1
    int j = lane & 31;          // channel group [4j, 4j+4)
    int s0 = offs[v], e1 = s0 + deg[v];
    float adh = 0.f;
    if (lane < 8) adh = ad1[v * 8 + lane];
    float s = 0.f;
    float4 A0 = {0,0,0,0}, A1 = {0,0,0,0}, A2 = {0,0,0,0}, A3 = {0,0,0,0};
    for (int i = s0; i < e1; i++) {
        int u = csr[i];
        float w = 0.f;
        if (lane < 8) {
            float e = as1[u * 8 + lane] + adh;
            e = (e >= 0.f) ? e : NEG * e;
            w = __expf(e);
            s += w;
        }
        float w0 = __shfl(w, g, 64);
        float w1 = __shfl(w, g + 2, 64);
        float w2 = __shfl(w, g + 4, 64);
        float w3 = __shfl(w, g + 6, 64);
        float4 xv = *(const float4*)(x + (size_t)u * 128 + j * 4);
        A0.x = fmaf(w0, xv.x, A0.x); A0.y = fmaf(w0, xv.y, A0.y);
        A0.z = fmaf(w0, xv.z, A0.z); A0.w = fmaf(w0, xv.w, A0.w);
        A1.x = fmaf(w1, xv.x, A1.x); A1.y = fmaf(w1, xv.y, A1.y);
        A1.z = fmaf(w1, xv.z, A1.z); A1.w = fmaf(w1, xv.w, A1.w);
        A2.x = fmaf(w2, xv.x, A2.x); A2.y = fmaf(w2, xv.y, A2.y);
        A2.z = fmaf(w2, xv.z, A2.z); A2.w = fmaf(w2, xv.w, A2.w);
        A3.x = fmaf(w3, xv.x, A3.x); A3.y = fmaf(w3, xv.y, A3.y);
        A3.z = fmaf(w3, xv.z, A3.z); A3.w = fmaf(w3, xv.w, A3.w);
    }
    float inv0 = 1.0f / __shfl(s, g, 64);
    float inv1 = 1.0f / __shfl(s, g + 2, 64);
    float inv2 = 1.0f / __shfl(s, g + 4, 64);
    float inv3 = 1.0f / __shfl(s, g + 6, 64);
    float4 As[4] = {A0, A1, A2, A3};
    float invs[4] = {inv0, inv1, inv2, inv3};
    #pragma unroll
    for (int t = 0; t < 4; t++) {
        int hh = g + 2 * t;
        float v0 = As[t].x * invs[t], v1 = As[t].y * invs[t];
        float v2 = As[t].z * invs[t], v3 = As[t].w * invs[t];
        unsigned short h0 = f2bf(v0), h1 = f2bf(v1), h2v = f2bf(v2), h3 = f2bf(v3);
        unsigned short l0 = f2bf(v0 - bf2f(h0)), l1 = f2bf(v1 - bf2f(h1));
        unsigned short l2 = f2bf(v2 - bf2f(h2v)), l3 = f2bf(v3 - bf2f(h3));
        uint2 hi, lo;
        hi.x = (unsigned)h0 | ((unsigned)h1 << 16);
        hi.y = (unsigned)h2v | ((unsigned)h3 << 16);
        lo.x = (unsigned)l0 | ((unsigned)l1 << 16);
        lo.y = (unsigned)l2 | ((unsigned)l3 << 16);
        size_t base = (size_t)v * 1024 + hh * 128 + j * 4;
        *(uint2*)(agghi + base) = hi;
        *(uint2*)(agglo + base) = lo;
    }
}

// ---------------------------------------------------------------- GEMM2 (MFMA, hi/lo A)
// per head h: val[row,col] = ELU((agghi+agglo)[row,h,:]@W1_h[:,col] + b1); project
// through W2, atomicAdd into h2[row,0:2]. x2 never materialized.
__global__ __launch_bounds__(256) void k_gemm2(const unsigned short* __restrict__ agghi,
                                               const unsigned short* __restrict__ agglo,
                                               const unsigned short* __restrict__ w1t,
                                               const float* __restrict__ b1,
                                               const float* __restrict__ W2,
                                               float* __restrict__ h2, int n) {
    int tid = threadIdx.x, wave = tid >> 6, lane = tid & 63;
    int l15 = lane & 15, q = lane >> 4;
    int h = blockIdx.y, col0 = h * 64;
    int row0 = blockIdx.x * 64 + wave * 16;
    f32x4 acc[4] = {};
    size_t abase = (size_t)(row0 + l15) * 1024 + h * 128 + q * 8;
    #pragma unroll
    for (int kb = 0; kb < 4; kb++) {
        bf16x8 ahi = *(const bf16x8*)(agghi + abase + kb * 32);
        bf16x8 alo = *(const bf16x8*)(agglo + abase + kb * 32);
        #pragma unroll
        for (int t = 0; t < 4; t++) {
            const unsigned short* bp =
                w1t + (size_t)(col0 + t * 16 + l15) * 128 + kb * 32 + q * 8;
            bf16x8 bf = *(const bf16x8*)bp;
            acc[t] = __builtin_amdgcn_mfma_f32_16x16x32_bf16(ahi, bf, acc[t], 0, 0, 0);
            acc[t] = __builtin_amdgcn_mfma_f32_16x16x32_bf16(alo, bf, acc[t], 0, 0, 0);
        }
    }
    float p0[4] = {}, p1[4] = {};
    #pragma unroll
    for (int t = 0; t < 4; t++) {
        int col = col0 + t * 16 + l15;
        float bb = b1[col];
        float2 w2v = *(const float2*)(W2 + 2 * col);
        #pragma unroll
        for (int r = 0; r < 4; r++) {
            float val = acc[t][r] + bb;
            val = (val > 0.f) ? val : (__expf(val) - 1.0f);
            p0[r] = fmaf(val, w2v.x, p0[r]);
            p1[r] = fmaf(val, w2v.y, p1[r]);
        }
    }
    #pragma unroll
    for (int r = 0; r < 4; r++) {
        #pragma unroll
        for (int off = 1; off < 16; off <<= 1) {
            p0[r] += __shfl_xor(p0[r], off, 64);
            p1[r] += __shfl_xor(p1[r], off, 64);
        }
    }
    if (l15 < 4) {
        float q0 = p0[0], q1 = p1[0];
        if (l15 == 1) { q0 = p0[1]; q1 = p1[1]; }
        if (l15 == 2) { q0 = p0[2]; q1 = p1[2]; }
        if (l15 == 3) { q0 = p0[3]; q1 = p1[3]; }
        int row = row0 + q * 4 + l15;
        if (row < n) {
            atomicAdd(&h2[2 * row],     q0);
            atomicAdd(&h2[2 * row + 1], q1);
        }
    }
}

// ---------------------------------------------------------------- agg layer 2
// 8 lanes per node (8 nodes per wave, 32 per block).
__global__ __launch_bounds__(256) void k_agg2(const float* __restrict__ h2,
                                              const float* __restrict__ a_src2,
                                              const float* __restrict__ a_dst2,
                                              const float* __restrict__ b2,
                                              const int* __restrict__ offs,
                                              const int* __restrict__ deg,
                                              const int* __restrict__ csr,
                                              float* __restrict__ out, int n) {
    int tid = threadIdx.x;
    int lane = tid & 63, wave = tid >> 6;
    int sub = lane & 7, g = lane >> 3;
    int v = blockIdx.x * 32 + wave * 8 + g;
    if (v >= n) return;
    int s0 = offs[v], s1 = s0 + deg[v];
    float sa0 = a_src2[0], sa1 = a_src2[1];
    float da0 = a_dst2[0], da1 = a_dst2[1];
    float2 hv = *(const float2*)(h2 + 2 * v);
    float adv = hv.x * da0 + hv.y * da1;
    float s = 0.f, a0 = 0.f, a1 = 0.f;
    for (int i = s0 + sub; i < s1; i += 8) {
        int u = csr[i];
        float2 hu = *(const float2*)(h2 + 2 * u);
        float e = hu.x * sa0 + hu.y * sa1 + adv;
        e = (e >= 0.f) ? e : NEG * e;
        float w = __expf(e);
        s += w;
        a0 = fmaf(w, hu.x, a0);
        a1 = fmaf(w, hu.y, a1);
    }
    #pragma unroll
    for (int off = 1; off < 8; off <<= 1) {   // stays within the 8-lane group
        s  += __shfl_xor(s, off, 64);
        a0 += __shfl_xor(a0, off, 64);
        a1 += __shfl_xor(a1, off, 64);
    }
    if (sub == 0) {
        float inv = 1.0f / s;
        out[2 * v]     = a0 * inv + b2[0];
        out[2 * v + 1] = a1 * inv + b2[1];
    }
}

// ---------------------------------------------------------------- launch
extern "C" void kernel_launch(void* const* d_in, const int* in_sizes, int n_in,
                              void* d_out, int out_size, void* d_ws, size_t ws_size,
                              hipStream_t stream) {
    const float* x      = (const float*)d_in[0];
    const int*   ei     = (const int*)d_in[1];
    const float* W1     = (const float*)d_in[2];
    const float* a_src1 = (const float*)d_in[3];
    const float* a_dst1 = (const float*)d_in[4];
    const float* b1     = (const float*)d_in[5];
    const float* W2     = (const float*)d_in[6];
    const float* a_src2 = (const float*)d_in[7];
    const float* a_dst2 = (const float*)d_in[8];
    const float* b2     = (const float*)d_in[9];
    float* out = (float*)d_out;

    int n  = in_sizes[0] / 128;   // 50000
    int E_ = in_sizes[1] / 2;     // 800000
    int tot = E_ + n;
    int rblk = (n + 63) / 64;     // 782
    int npad = rblk * 64;         // 50048

    char* w = (char*)d_ws;
    auto alloc = [&](size_t bytes) {
        char* p = w; w += (bytes + 255) & ~(size_t)255; return p;
    };
    int*            deg    = (int*)alloc((size_t)n * 4);
    int*            offs   = (int*)alloc((size_t)n * 4);
    int*            cursor = (int*)alloc((size_t)n * 4);
    int*            total  = (int*)alloc(256);
    int*            csr    = (int*)alloc((size_t)tot * 4);
    unsigned short* w1t    = (unsigned short*)alloc((size_t)512 * 128 * 2);
    unsigned short* cbhi   = (unsigned short*)alloc((size_t)16 * 128 * 2);
    unsigned short* cblo   = (unsigned short*)alloc((size_t)16 * 128 * 2);
    float*          as1    = (float*)alloc((size_t)n * 8 * 4);
    float*          ad1    = (float*)alloc((size_t)n * 8 * 4);
    unsigned short* agghi  = (unsigned short*)alloc((size_t)npad * 1024 * 2);
    unsigned short* agglo  = (unsigned short*)alloc((size_t)npad * 1024 * 2);
    float*          h2     = (float*)alloc((size_t)n * 2 * 4);

    int eb = (tot + 255) / 256;
    int zb = (2 * n + 255) / 256;
    int nb256 = (n + 255) / 256;
    k_zero<<<zb, 256, 0, stream>>>(deg, h2, total, n);
    k_count<<<eb, 256, 0, stream>>>(ei, deg, E_, n);
    k_assign<<<nb256, 256, 0, stream>>>(deg, offs, cursor, total, n);
    k_scatter<<<eb, 256, 0, stream>>>(ei, cursor, csr, E_, n);

    k_cast_wt<<<(512 * 128) / 256, 256, 0, stream>>>(W1, w1t);
    k_prep_c<<<8, 256, 0, stream>>>(W1, a_src1, a_dst1, cbhi, cblo);

    k_alpha<<<rblk, 256, 0, stream>>>(x, cbhi, cblo, as1, ad1, n);

    int nb = (n + 3) / 4;
    k_aggx<<<nb, 256, 0, stream>>>(x, as1, ad1, offs, deg, csr, agghi, agglo, n);

    dim3 g2(rblk, 8);
    k_gemm2<<<g2, 256, 0, stream>>>(agghi, agglo, w1t, b1, W2, h2, n);

    int ab = (n + 31) / 32;
    k_agg2<<<ab, 256, 0, stream>>>(h2, a_src2, a_dst2, b2, offs, deg, csr, out, n);
}

// Round 9
// 408.405 us; speedup vs baseline: 1.3615x; 1.0551x over previous
//
#include <hip/hip_runtime.h>
#include <hip/hip_bf16.h>

#define NEG 0.2f

typedef __attribute__((ext_vector_type(8))) short bf16x8;
typedef __attribute__((ext_vector_type(4))) float f32x4;

static __device__ __forceinline__ unsigned short f2bf(float f) {
    union { float f; unsigned u; } v; v.f = f;
    unsigned r = v.u + 0x7fff + ((v.u >> 16) & 1);
    return (unsigned short)(r >> 16);
}
static __device__ __forceinline__ float bf_lo(unsigned u) {
    return __uint_as_float(u << 16);
}
static __device__ __forceinline__ float bf_hi(unsigned u) {
    return __uint_as_float(u & 0xffff0000u);
}

// ---------------------------------------------------------------- init
__global__ void k_zero(int* __restrict__ deg, int* __restrict__ total, int n) {
    int i = blockIdx.x * 256 + threadIdx.x;
    if (i < n) deg[i] = 0;
    if (i == 0) *total = 0;
}

__global__ void k_count(const int* __restrict__ ei, int* __restrict__ deg,
                        int E_, int n) {
    int e = blockIdx.x * 256 + threadIdx.x;
    int tot = E_ + n;
    if (e >= tot) return;
    int d = (e < E_) ? ei[E_ + e] : (e - E_);
    atomicAdd(&deg[d], 1);
}

// parallel offset assignment (order-free CSR: offs need not be monotone)
__global__ void k_assign(const int* __restrict__ deg, int* __restrict__ offs,
                         int* __restrict__ cursor, int* __restrict__ total, int n) {
    int v = blockIdx.x * 256 + threadIdx.x;
    if (v >= n) return;
    int d = deg[v];
    int base = atomicAdd(total, d);
    offs[v] = base; cursor[v] = base;
}

__global__ void k_scatter(const int* __restrict__ ei, int* __restrict__ cursor,
                          int* __restrict__ csr, int E_, int n) {
    int e = blockIdx.x * 256 + threadIdx.x;
    int tot = E_ + n;
    if (e >= tot) return;
    int s, d;
    if (e < E_) { s = ei[e]; d = ei[E_ + e]; } else { s = d = e - E_; }
    int pos = atomicAdd(&cursor[d], 1);
    csr[pos] = s;
}

// ---------------------------------------------------------------- casts
// x [n,128] fp32 -> xb bf16, zero-padded to npad rows
__global__ void k_cast_x(const float* __restrict__ x, unsigned short* __restrict__ xb,
                         int nelem, int nelem_pad) {
    int i = (blockIdx.x * 256 + threadIdx.x) * 4;
    if (i >= nelem_pad) return;
    float4 v = (i < nelem) ? *(const float4*)(x + i) : make_float4(0, 0, 0, 0);
    ushort4 o;
    o.x = f2bf(v.x); o.y = f2bf(v.y); o.z = f2bf(v.z); o.w = f2bf(v.w);
    *(ushort4*)(xb + i) = o;
}

// W1 [128][512] -> W1t bf16 [512][128]
__global__ void k_cast_wt(const float* __restrict__ W, unsigned short* __restrict__ wt) {
    int i = blockIdx.x * 256 + threadIdx.x;   // 65536
    int c = i >> 7, k = i & 127;
    wt[i] = f2bf(W[k * 512 + c]);
}

// ---------------------------------------------------------------- GEMM1 (MFMA)
// h1b[n,512](bf16) = xb[n,128] @ W1[128,512]; alpha scores fused from the fp32
// accumulators (EXACT w.r.t. the bf16 GEMM — the R2-proven score path).
// Grid (rblk, 8): block = 4 waves x 16-row strips, head j = blockIdx.y.
__global__ __launch_bounds__(256) void k_gemm1(const unsigned short* __restrict__ xb,
                                               const unsigned short* __restrict__ w1t,
                                               const float* __restrict__ a_src,
                                               const float* __restrict__ a_dst,
                                               unsigned short* __restrict__ h1b,
                                               float* __restrict__ as1,
                                               float* __restrict__ ad1, int n) {
    int tid = threadIdx.x;
    int wave = tid >> 6, lane = tid & 63;
    int l15 = lane & 15, q = lane >> 4;
    int j = blockIdx.y;
    int col0 = j * 64;
    int row0 = blockIdx.x * 64 + wave * 16;

    f32x4 acc[4] = {};
    const unsigned short* ap = xb + (size_t)(row0 + l15) * 128 + q * 8;
    #pragma unroll
    for (int kb = 0; kb < 4; kb++) {
        bf16x8 af = *(const bf16x8*)(ap + kb * 32);
        #pragma unroll
        for (int t = 0; t < 4; t++) {
            const unsigned short* bp =
                w1t + (size_t)(col0 + t * 16 + l15) * 128 + kb * 32 + q * 8;
            bf16x8 bfv = *(const bf16x8*)bp;
            acc[t] = __builtin_amdgcn_mfma_f32_16x16x32_bf16(af, bfv, acc[t], 0, 0, 0);
        }
    }
    // store h1 in bf16
    #pragma unroll
    for (int t = 0; t < 4; t++) {
        #pragma unroll
        for (int r = 0; r < 4; r++) {
            int row = row0 + q * 4 + r;
            if (row < n)
                h1b[(size_t)row * 512 + col0 + t * 16 + l15] = f2bf(acc[t][r]);
        }
    }
    // fused alpha: as1[row,j] = sum_c acc * a_src[j,c]  (fp32 exact)
    float asv[4], adv[4];
    #pragma unroll
    for (int t = 0; t < 4; t++) {
        asv[t] = a_src[j * 64 + t * 16 + l15];
        adv[t] = a_dst[j * 64 + t * 16 + l15];
    }
    float ps[4], pd[4];
    #pragma unroll
    for (int r = 0; r < 4; r++) {
        ps[r] = acc[0][r] * asv[0] + acc[1][r] * asv[1]
              + acc[2][r] * asv[2] + acc[3][r] * asv[3];
        pd[r] = acc[0][r] * adv[0] + acc[1][r] * adv[1]
              + acc[2][r] * adv[2] + acc[3][r] * adv[3];
        #pragma unroll
        for (int off = 1; off < 16; off <<= 1) {  // reduce within quad (16 lanes)
            ps[r] += __shfl_xor(ps[r], off, 64);
            pd[r] += __shfl_xor(pd[r], off, 64);
        }
    }
    if (l15 < 4) {
        int r = l15;
        float vps = ps[0], vpd = pd[0];
        if (r == 1) { vps = ps[1]; vpd = pd[1]; }
        if (r == 2) { vps = ps[2]; vpd = pd[2]; }
        if (r == 3) { vps = ps[3]; vpd = pd[3]; }
        int row = row0 + q * 4 + r;
        if (row < n) { as1[row * 8 + j] = vps; ad1[row * 8 + j] = vpd; }
    }
}

// ---------------------------------------------------------------- agg layer 1 (fused l2prep)
// One wave per dst node, single pass, unnormalized exp (fp32-safe range).
// Lane covers channels [8*lane, 8*lane+8), head = lane>>3.
// Epilogue: /s, +b1, ELU, project through W2 (512->2), butterfly-64, write h2.
// x2 is NEVER materialized, and never rounded to bf16.
__global__ __launch_bounds__(256) void k_agg1(const unsigned short* __restrict__ h1b,
                                              const float* __restrict__ as1,
                                              const float* __restrict__ ad1,
                                              const float* __restrict__ b1,
                                              const float* __restrict__ W2,
                                              const int* __restrict__ offs,
                                              const int* __restrict__ deg,
                                              const int* __restrict__ csr,
                                              float* __restrict__ h2, int n) {
    int lane = threadIdx.x & 63;
    int v = blockIdx.x * 4 + (threadIdx.x >> 6);
    if (v >= n) return;
    int head = lane >> 3, c = lane * 8;
    int s0 = offs[v], e1 = s0 + deg[v];
    float adh = ad1[v * 8 + head];
    float s = 0.f;
    float acc[8] = {};
    for (int i = s0; i < e1; i++) {
        int u = csr[i];
        float e = as1[u * 8 + head] + adh;
        e = (e >= 0.f) ? e : NEG * e;
        float w = __expf(e);
        s += w;
        uint4 hv = *(const uint4*)(h1b + (size_t)u * 512 + c);
        acc[0] = fmaf(w, bf_lo(hv.x), acc[0]);
        acc[1] = fmaf(w, bf_hi(hv.x), acc[1]);
        acc[2] = fmaf(w, bf_lo(hv.y), acc[2]);
        acc[3] = fmaf(w, bf_hi(hv.y), acc[3]);
        acc[4] = fmaf(w, bf_lo(hv.z), acc[4]);
        acc[5] = fmaf(w, bf_hi(hv.z), acc[5]);
        acc[6] = fmaf(w, bf_lo(hv.w), acc[6]);
        acc[7] = fmaf(w, bf_hi(hv.w), acc[7]);
    }
    float inv = 1.0f / s;
    float4 ba = *(const float4*)(b1 + c);
    float4 bb = *(const float4*)(b1 + c + 4);
    float o[8] = {acc[0] * inv + ba.x, acc[1] * inv + ba.y,
                  acc[2] * inv + ba.z, acc[3] * inv + ba.w,
                  acc[4] * inv + bb.x, acc[5] * inv + bb.y,
                  acc[6] * inv + bb.z, acc[7] * inv + bb.w};
    #pragma unroll
    for (int jj = 0; jj < 8; jj++)
        o[jj] = (o[jj] > 0.f) ? o[jj] : (__expf(o[jj]) - 1.0f);
    // project through W2 (exactly R2's proven l2prep arithmetic)
    const float4* wp = (const float4*)(W2 + c * 2);
    float4 w0 = wp[0], w1 = wp[1], w2 = wp[2], w3 = wp[3];
    float p0 = o[0] * w0.x + o[1] * w0.z + o[2] * w1.x + o[3] * w1.z
             + o[4] * w2.x + o[5] * w2.z + o[6] * w3.x + o[7] * w3.z;
    float p1 = o[0] * w0.y + o[1] * w0.w + o[2] * w1.y + o[3] * w1.w
             + o[4] * w2.y + o[5] * w2.w + o[6] * w3.y + o[7] * w3.w;
    #pragma unroll
    for (int off = 1; off < 64; off <<= 1) {
        p0 += __shfl_xor(p0, off, 64);
        p1 += __shfl_xor(p1, off, 64);
    }
    if (lane == 0) {
        h2[2 * v] = p0;
        h2[2 * v + 1] = p1;
    }
}

// ---------------------------------------------------------------- agg layer 2
// 8 lanes per node; scores computed on the fly from h2 (L2-resident).
__global__ __launch_bounds__(256) void k_agg2(const float* __restrict__ h2,
                                              const float* __restrict__ a_src2,
                                              const float* __restrict__ a_dst2,
                                              const float* __restrict__ b2,
                                              const int* __restrict__ offs,
                                              const int* __restrict__ deg,
                                              const int* __restrict__ csr,
                                              float* __restrict__ out, int n) {
    int tid = threadIdx.x;
    int lane = tid & 63, wave = tid >> 6;
    int sub = lane & 7, g = lane >> 3;
    int v = blockIdx.x * 32 + wave * 8 + g;
    if (v >= n) return;
    int s0 = offs[v], s1 = s0 + deg[v];
    float sa0 = a_src2[0], sa1 = a_src2[1];
    float da0 = a_dst2[0], da1 = a_dst2[1];
    float2 hv = *(const float2*)(h2 + 2 * v);
    float adv = hv.x * da0 + hv.y * da1;
    float s = 0.f, a0 = 0.f, a1 = 0.f;
    for (int i = s0 + sub; i < s1; i += 8) {
        int u = csr[i];
        float2 hu = *(const float2*)(h2 + 2 * u);
        float e = hu.x * sa0 + hu.y * sa1 + adv;
        e = (e >= 0.f) ? e : NEG * e;
        float w = __expf(e);
        s += w;
        a0 = fmaf(w, hu.x, a0);
        a1 = fmaf(w, hu.y, a1);
    }
    #pragma unroll
    for (int off = 1; off < 8; off <<= 1) {   // stays within the 8-lane group
        s  += __shfl_xor(s, off, 64);
        a0 += __shfl_xor(a0, off, 64);
        a1 += __shfl_xor(a1, off, 64);
    }
    if (sub == 0) {
        float inv = 1.0f / s;
        out[2 * v]     = a0 * inv + b2[0];
        out[2 * v + 1] = a1 * inv + b2[1];
    }
}

// ---------------------------------------------------------------- launch
extern "C" void kernel_launch(void* const* d_in, const int* in_sizes, int n_in,
                              void* d_out, int out_size, void* d_ws, size_t ws_size,
                              hipStream_t stream) {
    const float* x      = (const float*)d_in[0];
    const int*   ei     = (const int*)d_in[1];
    const float* W1     = (const float*)d_in[2];
    const float* a_src1 = (const float*)d_in[3];
    const float* a_dst1 = (const float*)d_in[4];
    const float* b1     = (const float*)d_in[5];
    const float* W2     = (const float*)d_in[6];
    const float* a_src2 = (const float*)d_in[7];
    const float* a_dst2 = (const float*)d_in[8];
    const float* b2     = (const float*)d_in[9];
    float* out = (float*)d_out;

    int n  = in_sizes[0] / 128;   // 50000
    int E_ = in_sizes[1] / 2;     // 800000
    int tot = E_ + n;
    int rblk = (n + 63) / 64;     // 782
    int npad = rblk * 64;         // 50048

    char* w = (char*)d_ws;
    auto alloc = [&](size_t bytes) {
        char* p = w; w += (bytes + 255) & ~(size_t)255; return p;
    };
    int*            deg    = (int*)alloc((size_t)n * 4);
    int*            offs   = (int*)alloc((size_t)n * 4);
    int*            cursor = (int*)alloc((size_t)n * 4);
    int*            total  = (int*)alloc(256);
    int*            csr    = (int*)alloc((size_t)tot * 4);
    unsigned short* xb     = (unsigned short*)alloc((size_t)npad * 128 * 2);
    unsigned short* w1t    = (unsigned short*)alloc((size_t)512 * 128 * 2);
    unsigned short* h1b    = (unsigned short*)alloc((size_t)npad * 512 * 2);
    float*          as1    = (float*)alloc((size_t)n * 8 * 4);
    float*          ad1    = (float*)alloc((size_t)n * 8 * 4);
    float*          h2     = (float*)alloc((size_t)n * 2 * 4);

    int eb = (tot + 255) / 256;
    int nb256 = (n + 255) / 256;
    k_zero<<<nb256, 256, 0, stream>>>(deg, total, n);
    k_count<<<eb, 256, 0, stream>>>(ei, deg, E_, n);
    k_assign<<<nb256, 256, 0, stream>>>(deg, offs, cursor, total, n);
    k_scatter<<<eb, 256, 0, stream>>>(ei, cursor, csr, E_, n);

    int xel = n * 128, xelp = npad * 128;
    k_cast_x<<<(xelp / 4 + 255) / 256, 256, 0, stream>>>(x, xb, xel, xelp);
    k_cast_wt<<<(512 * 128) / 256, 256, 0, stream>>>(W1, w1t);

    dim3 g1(rblk, 8);
    k_gemm1<<<g1, 256, 0, stream>>>(xb, w1t, a_src1, a_dst1, h1b, as1, ad1, n);

    int nb = (n + 3) / 4;
    k_agg1<<<nb, 256, 0, stream>>>(h1b, as1, ad1, b1, W2, offs, deg, csr, h2, n);

    int ab = (n + 31) / 32;
    k_agg2<<<ab, 256, 0, stream>>>(h2, a_src2, a_dst2, b2, offs, deg, csr, out, n);
}

// Round 10
// 369.229 us; speedup vs baseline: 1.5059x; 1.1061x over previous
//
#include <hip/hip_runtime.h>
#include <hip/hip_bf16.h>

#define NEG 0.2f

typedef __attribute__((ext_vector_type(8))) short bf16x8;
typedef __attribute__((ext_vector_type(4))) float f32x4;

static __device__ __forceinline__ unsigned short f2bf(float f) {
    union { float f; unsigned u; } v; v.f = f;
    unsigned r = v.u + 0x7fff + ((v.u >> 16) & 1);
    return (unsigned short)(r >> 16);
}
static __device__ __forceinline__ float bf_lo(unsigned u) {
    return __uint_as_float(u << 16);
}
static __device__ __forceinline__ float bf_hi(unsigned u) {
    return __uint_as_float(u & 0xffff0000u);
}

// ---------------------------------------------------------------- setup (fused)
// segment A: zero deg[n] + total; segment B: W1 -> W1t bf16 [512][128];
// segment C: x -> xb bf16, zero-padded to npad rows.
__global__ void k_setup(const float* __restrict__ x, const float* __restrict__ W1,
                        unsigned short* __restrict__ xb, unsigned short* __restrict__ wt,
                        int* __restrict__ deg, int* __restrict__ total,
                        int n, int xel, int xelp) {
    int gid = blockIdx.x * 256 + threadIdx.x;
    if (gid < n) {
        deg[gid] = 0;
        if (gid == 0) *total = 0;
        return;
    }
    int i = gid - n;
    if (i < 65536) {           // cast W1t
        int c = i >> 7, k = i & 127;
        wt[i] = f2bf(W1[k * 512 + c]);
        return;
    }
    int i4 = (i - 65536) * 4;  // cast x (padded)
    if (i4 >= xelp) return;
    float4 v = (i4 < xel) ? *(const float4*)(x + i4) : make_float4(0, 0, 0, 0);
    ushort4 o;
    o.x = f2bf(v.x); o.y = f2bf(v.y); o.z = f2bf(v.z); o.w = f2bf(v.w);
    *(ushort4*)(xb + i4) = o;
}

// ---------------------------------------------------------------- CSR build
__global__ void k_count(const int* __restrict__ ei, int* __restrict__ deg,
                        int E_, int n) {
    int e = blockIdx.x * 256 + threadIdx.x;
    int tot = E_ + n;
    if (e >= tot) return;
    int d = (e < E_) ? ei[E_ + e] : (e - E_);
    atomicAdd(&deg[d], 1);
}

// parallel offset assignment (order-free CSR: offs need not be monotone)
__global__ void k_assign(const int* __restrict__ deg, int* __restrict__ offs,
                         int* __restrict__ cursor, int* __restrict__ total, int n) {
    int v = blockIdx.x * 256 + threadIdx.x;
    if (v >= n) return;
    int d = deg[v];
    int base = atomicAdd(total, d);
    offs[v] = base; cursor[v] = base;
}

__global__ void k_scatter(const int* __restrict__ ei, int* __restrict__ cursor,
                          int* __restrict__ csr, int E_, int n) {
    int e = blockIdx.x * 256 + threadIdx.x;
    int tot = E_ + n;
    if (e >= tot) return;
    int s, d;
    if (e < E_) { s = ei[e]; d = ei[E_ + e]; } else { s = d = e - E_; }
    int pos = atomicAdd(&cursor[d], 1);
    csr[pos] = s;
}

// ---------------------------------------------------------------- GEMM1 (MFMA)
// h1b[n,512](bf16) = xb[n,128] @ W1[128,512]; alpha scores fused from the fp32
// accumulators (EXACT w.r.t. the bf16 GEMM — the R2/R9-proven score path).
// Grid ((n+255)/256, 8): 4 waves x 64 rows; B-fragments register-resident,
// reused across 4 row-subtiles (B L2 traffic / 4 vs R9).
__global__ __launch_bounds__(256) void k_gemm1(const unsigned short* __restrict__ xb,
                                               const unsigned short* __restrict__ w1t,
                                               const float* __restrict__ a_src,
                                               const float* __restrict__ a_dst,
                                               unsigned short* __restrict__ h1b,
                                               float* __restrict__ as1,
                                               float* __restrict__ ad1, int n) {
    int tid = threadIdx.x;
    int wave = tid >> 6, lane = tid & 63;
    int l15 = lane & 15, q = lane >> 4;
    int j = blockIdx.y;
    int col0 = j * 64;
    int rowblk = blockIdx.x * 256 + wave * 64;

    bf16x8 bfr[4][4];   // [kb][t]
    #pragma unroll
    for (int kb = 0; kb < 4; kb++)
        #pragma unroll
        for (int t = 0; t < 4; t++)
            bfr[kb][t] = *(const bf16x8*)(w1t + (size_t)(col0 + t * 16 + l15) * 128
                                          + kb * 32 + q * 8);
    float asv[4], adv[4];
    #pragma unroll
    for (int t = 0; t < 4; t++) {
        asv[t] = a_src[j * 64 + t * 16 + l15];
        adv[t] = a_dst[j * 64 + t * 16 + l15];
    }

    #pragma unroll
    for (int st = 0; st < 4; st++) {
        int row0 = rowblk + st * 16;
        f32x4 acc[4] = {};
        const unsigned short* ap = xb + (size_t)(row0 + l15) * 128 + q * 8;
        #pragma unroll
        for (int kb = 0; kb < 4; kb++) {
            bf16x8 af = *(const bf16x8*)(ap + kb * 32);
            #pragma unroll
            for (int t = 0; t < 4; t++)
                acc[t] = __builtin_amdgcn_mfma_f32_16x16x32_bf16(af, bfr[kb][t], acc[t], 0, 0, 0);
        }
        // store h1 in bf16
        #pragma unroll
        for (int t = 0; t < 4; t++) {
            #pragma unroll
            for (int r = 0; r < 4; r++) {
                int row = row0 + q * 4 + r;
                if (row < n)
                    h1b[(size_t)row * 512 + col0 + t * 16 + l15] = f2bf(acc[t][r]);
            }
        }
        // fused alpha: as1[row,j] = sum_c acc * a_src[j,c]  (fp32 exact)
        float ps[4], pd[4];
        #pragma unroll
        for (int r = 0; r < 4; r++) {
            ps[r] = acc[0][r] * asv[0] + acc[1][r] * asv[1]
                  + acc[2][r] * asv[2] + acc[3][r] * asv[3];
            pd[r] = acc[0][r] * adv[0] + acc[1][r] * adv[1]
                  + acc[2][r] * adv[2] + acc[3][r] * adv[3];
            #pragma unroll
            for (int off = 1; off < 16; off <<= 1) {
                ps[r] += __shfl_xor(ps[r], off, 64);
                pd[r] += __shfl_xor(pd[r], off, 64);
            }
        }
        if (l15 < 4) {
            int r = l15;
            float vps = ps[0], vpd = pd[0];
            if (r == 1) { vps = ps[1]; vpd = pd[1]; }
            if (r == 2) { vps = ps[2]; vpd = pd[2]; }
            if (r == 3) { vps = ps[3]; vpd = pd[3]; }
            int row = row0 + q * 4 + r;
            if (row < n) { as1[row * 8 + j] = vps; ad1[row * 8 + j] = vpd; }
        }
    }
}

// ---------------------------------------------------------------- agg layer 1 (fused l2prep)
// One wave per dst node, single pass, unnormalized exp, 2x-unrolled edge loop
// (doubles gather MLP — kernel is latency-bound: 42% HBM path, 39% VALU).
// Lane covers channels [8*lane, 8*lane+8), head = lane>>3.
// Epilogue: /s, +b1, ELU, project through W2 (512->2), butterfly-64, write h2.
__global__ __launch_bounds__(256) void k_agg1(const unsigned short* __restrict__ h1b,
                                              const float* __restrict__ as1,
                                              const float* __restrict__ ad1,
                                              const float* __restrict__ b1,
                                              const float* __restrict__ W2,
                                              const int* __restrict__ offs,
                                              const int* __restrict__ deg,
                                              const int* __restrict__ csr,
                                              float* __restrict__ h2, int n) {
    int lane = threadIdx.x & 63;
    int v = blockIdx.x * 4 + (threadIdx.x >> 6);
    if (v >= n) return;
    int head = lane >> 3, c = lane * 8;
    int s0 = offs[v], e1 = s0 + deg[v];
    float adh = ad1[v * 8 + head];
    float s = 0.f;
    float acc[8] = {};
    int i = s0;
    for (; i + 2 <= e1; i += 2) {
        int u0 = csr[i], u1 = csr[i + 1];
        float ea = as1[u0 * 8 + head] + adh;
        float eb = as1[u1 * 8 + head] + adh;
        uint4 h0 = *(const uint4*)(h1b + (size_t)u0 * 512 + c);
        uint4 h1 = *(const uint4*)(h1b + (size_t)u1 * 512 + c);
        ea = (ea >= 0.f) ? ea : NEG * ea;
        eb = (eb >= 0.f) ? eb : NEG * eb;
        float w0 = __expf(ea), w1 = __expf(eb);
        s += w0 + w1;
        acc[0] = fmaf(w0, bf_lo(h0.x), fmaf(w1, bf_lo(h1.x), acc[0]));
        acc[1] = fmaf(w0, bf_hi(h0.x), fmaf(w1, bf_hi(h1.x), acc[1]));
        acc[2] = fmaf(w0, bf_lo(h0.y), fmaf(w1, bf_lo(h1.y), acc[2]));
        acc[3] = fmaf(w0, bf_hi(h0.y), fmaf(w1, bf_hi(h1.y), acc[3]));
        acc[4] = fmaf(w0, bf_lo(h0.z), fmaf(w1, bf_lo(h1.z), acc[4]));
        acc[5] = fmaf(w0, bf_hi(h0.z), fmaf(w1, bf_hi(h1.z), acc[5]));
        acc[6] = fmaf(w0, bf_lo(h0.w), fmaf(w1, bf_lo(h1.w), acc[6]));
        acc[7] = fmaf(w0, bf_hi(h0.w), fmaf(w1, bf_hi(h1.w), acc[7]));
    }
    if (i < e1) {
        int u = csr[i];
        float e = as1[u * 8 + head] + adh;
        e = (e >= 0.f) ? e : NEG * e;
        float w = __expf(e);
        s += w;
        uint4 hv = *(const uint4*)(h1b + (size_t)u * 512 + c);
        acc[0] = fmaf(w, bf_lo(hv.x), acc[0]);
        acc[1] = fmaf(w, bf_hi(hv.x), acc[1]);
        acc[2] = fmaf(w, bf_lo(hv.y), acc[2]);
        acc[3] = fmaf(w, bf_hi(hv.y), acc[3]);
        acc[4] = fmaf(w, bf_lo(hv.z), acc[4]);
        acc[5] = fmaf(w, bf_hi(hv.z), acc[5]);
        acc[6] = fmaf(w, bf_lo(hv.w), acc[6]);
        acc[7] = fmaf(w, bf_hi(hv.w), acc[7]);
    }
    float inv = 1.0f / s;
    float4 ba = *(const float4*)(b1 + c);
    float4 bb = *(const float4*)(b1 + c + 4);
    float o[8] = {acc[0] * inv + ba.x, acc[1] * inv + ba.y,
                  acc[2] * inv + ba.z, acc[3] * inv + ba.w,
                  acc[4] * inv + bb.x, acc[5] * inv + bb.y,
                  acc[6] * inv + bb.z, acc[7] * inv + bb.w};
    #pragma unroll
    for (int jj = 0; jj < 8; jj++)
        o[jj] = (o[jj] > 0.f) ? o[jj] : (__expf(o[jj]) - 1.0f);
    // project through W2 (R2-proven l2prep arithmetic)
    const float4* wp = (const float4*)(W2 + c * 2);
    float4 w0 = wp[0], w1 = wp[1], w2 = wp[2], w3 = wp[3];
    float p0 = o[0] * w0.x + o[1] * w0.z + o[2] * w1.x + o[3] * w1.z
             + o[4] * w2.x + o[5] * w2.z + o[6] * w3.x + o[7] * w3.z;
    float p1 = o[0] * w0.y + o[1] * w0.w + o[2] * w1.y + o[3] * w1.w
             + o[4] * w2.y + o[5] * w2.w + o[6] * w3.y + o[7] * w3.w;
    #pragma unroll
    for (int off = 1; off < 64; off <<= 1) {
        p0 += __shfl_xor(p0, off, 64);
        p1 += __shfl_xor(p1, off, 64);
    }
    if (lane == 0) {
        h2[2 * v] = p0;
        h2[2 * v + 1] = p1;
    }
}

// ---------------------------------------------------------------- agg layer 2
// 8 lanes per node; scores computed on the fly from h2 (L2-resident).
__global__ __launch_bounds__(256) void k_agg2(const float* __restrict__ h2,
                                              const float* __restrict__ a_src2,
                                              const float* __restrict__ a_dst2,
                                              const float* __restrict__ b2,
                                              const int* __restrict__ offs,
                                              const int* __restrict__ deg,
                                              const int* __restrict__ csr,
                                              float* __restrict__ out, int n) {
    int tid = threadIdx.x;
    int lane = tid & 63, wave = tid >> 6;
    int sub = lane & 7, g = lane >> 3;
    int v = blockIdx.x * 32 + wave * 8 + g;
    if (v >= n) return;
    int s0 = offs[v], s1 = s0 + deg[v];
    float sa0 = a_src2[0], sa1 = a_src2[1];
    float da0 = a_dst2[0], da1 = a_dst2[1];
    float2 hv = *(const float2*)(h2 + 2 * v);
    float adv = hv.x * da0 + hv.y * da1;
    float s = 0.f, a0 = 0.f, a1 = 0.f;
    for (int i = s0 + sub; i < s1; i += 8) {
        int u = csr[i];
        float2 hu = *(const float2*)(h2 + 2 * u);
        float e = hu.x * sa0 + hu.y * sa1 + adv;
        e = (e >= 0.f) ? e : NEG * e;
        float w = __expf(e);
        s += w;
        a0 = fmaf(w, hu.x, a0);
        a1 = fmaf(w, hu.y, a1);
    }
    #pragma unroll
    for (int off = 1; off < 8; off <<= 1) {   // stays within the 8-lane group
        s  += __shfl_xor(s, off, 64);
        a0 += __shfl_xor(a0, off, 64);
        a1 += __shfl_xor(a1, off, 64);
    }
    if (sub == 0) {
        float inv = 1.0f / s;
        out[2 * v]     = a0 * inv + b2[0];
        out[2 * v + 1] = a1 * inv + b2[1];
    }
}

// ---------------------------------------------------------------- launch
extern "C" void kernel_launch(void* const* d_in, const int* in_sizes, int n_in,
                              void* d_out, int out_size, void* d_ws, size_t ws_size,
                              hipStream_t stream) {
    const float* x      = (const float*)d_in[0];
    const int*   ei     = (const int*)d_in[1];
    const float* W1     = (const float*)d_in[2];
    const float* a_src1 = (const float*)d_in[3];
    const float* a_dst1 = (const float*)d_in[4];
    const float* b1     = (const float*)d_in[5];
    const float* W2     = (const float*)d_in[6];
    const float* a_src2 = (const float*)d_in[7];
    const float* a_dst2 = (const float*)d_in[8];
    const float* b2     = (const float*)d_in[9];
    float* out = (float*)d_out;

    int n  = in_sizes[0] / 128;   // 50000
    int E_ = in_sizes[1] / 2;     // 800000
    int tot = E_ + n;
    int rblk = (n + 255) / 256;   // 196
    int npad = rblk * 256;        // 50176

    char* w = (char*)d_ws;
    auto alloc = [&](size_t bytes) {
        char* p = w; w += (bytes + 255) & ~(size_t)255; return p;
    };
    int*            deg    = (int*)alloc((size_t)n * 4);
    int*            offs   = (int*)alloc((size_t)n * 4);
    int*            cursor = (int*)alloc((size_t)n * 4);
    int*            total  = (int*)alloc(256);
    int*            csr    = (int*)alloc((size_t)tot * 4);
    unsigned short* xb     = (unsigned short*)alloc((size_t)npad * 128 * 2);
    unsigned short* w1t    = (unsigned short*)alloc((size_t)512 * 128 * 2);
    unsigned short* h1b    = (unsigned short*)alloc((size_t)npad * 512 * 2);
    float*          as1    = (float*)alloc((size_t)n * 8 * 4);
    float*          ad1    = (float*)alloc((size_t)n * 8 * 4);
    float*          h2     = (float*)alloc((size_t)n * 2 * 4);

    int xel = n * 128, xelp = npad * 128;
    int setup_work = n + 65536 + xelp / 4;
    k_setup<<<(setup_work + 255) / 256, 256, 0, stream>>>(x, W1, xb, w1t, deg, total,
                                                          n, xel, xelp);

    int eb = (tot + 255) / 256;
    int nb256 = (n + 255) / 256;
    k_count<<<eb, 256, 0, stream>>>(ei, deg, E_, n);
    k_assign<<<nb256, 256, 0, stream>>>(deg, offs, cursor, total, n);
    k_scatter<<<eb, 256, 0, stream>>>(ei, cursor, csr, E_, n);

    dim3 g1(rblk, 8);
    k_gemm1<<<g1, 256, 0, stream>>>(xb, w1t, a_src1, a_dst1, h1b, as1, ad1, n);

    int nb = (n + 3) / 4;
    k_agg1<<<nb, 256, 0, stream>>>(h1b, as1, ad1, b1, W2, offs, deg, csr, h2, n);

    int ab = (n + 31) / 32;
    k_agg2<<<ab, 256, 0, stream>>>(h2, a_src2, a_dst2, b2, offs, deg, csr, out, n);
}